// Round 6
// baseline (216.519 us; speedup 1.0000x reference)
//
#include <hip/hip_runtime.h>

// Hawkes log-likelihood, D=1024 dims, M=32768 events, BETA=1.
//
// lam_i = mu[d_i] + sum_{j<i} alpha[d_i,d_j] * exp(t_j - t_i).
// Chunk events into NC=512 chunks of C=64:
//   cross-chunk: exp(t_c0 - t_i) * dot(alpha[d_i,:], S_c)
//   in-chunk:    one lane-parallel predicated gather step (C == wave size)
// S_c via TWO-LEVEL dimension-parallel scan; level-1 histogram+scan fused in
// LDS; level-2 fixup S = Sl + Sg*cumdec fused into k_main's S load.
// Compensator: sum_i colsum[d_i] * (1 - exp(t_i - T)) fused into k_main.
//
// Lessons: R2 — same-cacheline global atomics serialize (~15ns) -> zero
// global atomics. R5 — single-block LDS-atomic histogram = 43us on one CU
// -> killed. R4/R5 — dispatch gaps + timed harness fills dominate -> FOUR
// dispatches total; k1 merges all input-only work with disjoint block roles
// (colsum recomputes softplus column-wise so it needs no producer kernel).
//
// ws floats: alpha[D*D] | Sl[NC*D] | mu[D] | colsum[D] | llp[NB] |
//            compp[NB] | A[NG*D] | Sg[NG*D] | cumdec[NC]   (~6.5 MB)

#define D 1024
#define M 32768
#define C 64
#define NC (M / C)   /* 512 */
#define NB (NC * 4)  /* k_main blocks: 2048 */
#define NG 16        /* scan groups */
#define GC (NC / NG) /* 32 chunks per group */
#define TMAXV 1000.0f
#define EPSMU 1e-6f
#define EPSLOG 1e-8f

__device__ __forceinline__ float softplus(float x) {
    return (x > 0.0f) ? (x + log1pf(__expf(-x))) : log1pf(__expf(x));
}

// One kernel, disjoint block roles; every role reads ONLY problem inputs:
//   b in [0,256):    alpha[4b..4b+3][:] = softplus(log_alpha rows)
//   b == 256:        mu = softplus(log_mu) + eps
//   b in [257,273):  colsum (16 blocks x 64 cols, column-wise softplus re-read)
//   b in [273,337):  fused level-1: per-chunk LDS histogram + LDS scan
__global__ void k1(const float* __restrict__ t_ev, const int* __restrict__ marks,
                   const float* __restrict__ log_alpha, const float* __restrict__ log_mu,
                   float* __restrict__ alpha, float* __restrict__ mu,
                   float* __restrict__ colsum, float* __restrict__ Sl,
                   float* __restrict__ A) {
    __shared__ float Lh[GC * 256];  // 32 KB (fused role)
    __shared__ float dec[GC];
    __shared__ float tns[GC];
    __shared__ float cred[4][64];   // colsum role
    int t = threadIdx.x;
    int b = blockIdx.x;

    if (b < 256) {
        int r0 = b * 4;
        for (int r = 0; r < 4; ++r) {
            size_t base = (size_t)(r0 + r) * D;
#pragma unroll
            for (int q = 0; q < 4; ++q) {
                int col = t + 256 * q;
                alpha[base + col] = softplus(log_alpha[base + col]);
            }
        }
    } else if (b == 256) {
#pragma unroll
        for (int q = 0; q < 4; ++q) {
            int k = t + 256 * q;
            mu[k] = softplus(log_mu[k]) + EPSMU;
        }
    } else if (b < 273) {
        int cb = b - 257;            // 0..15
        int col = cb * 64 + (t & 63);
        int rseg = t >> 6;           // 0..3: 256-row segment per wave
        float s = 0.0f;
#pragma unroll 8
        for (int r = rseg * 256; r < rseg * 256 + 256; ++r)
            s += softplus(log_alpha[(size_t)r * D + col]);
        cred[rseg][t & 63] = s;
        __syncthreads();
        if (t < 64)
            colsum[cb * 64 + t] = cred[0][t] + cred[1][t] + cred[2][t] + cred[3][t];
    } else {
        int fb = b - 273;            // 0..63
        int g = fb >> 2, db = fb & 3;
#pragma unroll
        for (int q = 0; q < GC; ++q) Lh[q * 256 + t] = 0.0f;
        if (t < GC) {
            int gc = g * GC + t;
            float tn = (gc + 1 < NC) ? t_ev[(gc + 1) * C] : t_ev[M - 1];
            tns[t] = tn;
            dec[t] = (gc + 1 < NC) ? __expf(t_ev[gc * C] - tn) : 1.0f;
        }
        __syncthreads();
        int base = g * (GC * C);  // 2048 events per group
#pragma unroll
        for (int it = 0; it < 8; ++it) {
            int e = it * 256 + t;
            float te = t_ev[base + e];
            int m = marks[base + e];
            int lc = e >> 6;
            int ml = m - db * 256;
            if ((unsigned)ml < 256u) atomicAdd(&Lh[lc * 256 + ml], __expf(te - tns[lc]));
        }
        __syncthreads();
        int k = db * 256 + t;
        float S = 0.0f;
        for (int lc = 0; lc < GC; ++lc) {
            Sl[(size_t)(g * GC + lc) * D + k] = S;
            S = S * dec[lc] + Lh[lc * 256 + t];
        }
        A[(size_t)g * D + k] = S;
    }
}

// Level-2 scan over the 16 group aggregates + per-chunk scalar cumdec.
__global__ void k_scanB(const float* __restrict__ t_ev, const float* __restrict__ A,
                        float* __restrict__ Sg, float* __restrict__ cumdec) {
    __shared__ float dec[NC];
    __shared__ float P[NG];
    int t = threadIdx.x;
    if (t < NC)
        dec[t] = (t + 1 < NC) ? __expf(t_ev[t * C] - t_ev[(t + 1) * C]) : 1.0f;
    __syncthreads();
    if (t < NC) {
        int g = t >> 5, r = t & 31;
        float p = 1.0f;
        for (int j = 0; j < r; ++j) p *= dec[g * GC + j];
        cumdec[t] = p;
        if (r == GC - 1) P[g] = p * dec[t];
    }
    __syncthreads();
    float a[NG];
#pragma unroll
    for (int g2 = 0; g2 < NG; ++g2) a[g2] = A[(size_t)g2 * D + t];
    float S = 0.0f;
#pragma unroll
    for (int g2 = 0; g2 < NG; ++g2) {
        Sg[(size_t)g2 * D + t] = S;
        S = S * P[g2] + a[g2];
    }
}

// main: 4 blocks per chunk (16 events each), fused scan fixup + compensator.
// Per-block partials, no global atomics.
__launch_bounds__(256)
__global__ void k_main(const float* __restrict__ t_ev, const int* __restrict__ marks,
                       const float* __restrict__ alpha, const float* __restrict__ mu,
                       const float* __restrict__ colsum, const float* __restrict__ Sl,
                       const float* __restrict__ Sg, const float* __restrict__ cumdec,
                       float* __restrict__ llp, float* __restrict__ compp) {
    __shared__ float S_lds[D];
    __shared__ float t_lds[C];
    __shared__ int d_lds[C];
    __shared__ float red[8];
    int t = threadIdx.x;
    int c = blockIdx.x >> 2, sub = blockIdx.x & 3;
    int g = c >> 5;
    float cd = cumdec[c];
#pragma unroll
    for (int q = 0; q < 4; ++q) {
        int k = t + 256 * q;
        S_lds[k] = Sl[(size_t)c * D + k] + Sg[(size_t)g * D + k] * cd;
    }
    if (t < C) {
        t_lds[t] = t_ev[c * C + t];
        d_lds[t] = marks[c * C + t];
    }
    __syncthreads();
    int wave = t >> 6, lane = t & 63;
    float t0 = t_lds[0];
    float ll_acc = 0.0f, comp_acc = 0.0f;
    for (int i = sub * 16 + wave; i < sub * 16 + 16; i += 4) {
        int row = d_lds[i];
        float ti = t_lds[i];
        float mu_r = mu[row];
        float cs_r = colsum[row];
        const float4* arow = (const float4*)(alpha + (size_t)row * D);
        const float4* srow = (const float4*)S_lds;
        float acc_dot = 0.0f;
#pragma unroll
        for (int u = 0; u < 4; ++u) {
            float4 a4 = arow[lane + 64 * u];
            float4 s4 = srow[lane + 64 * u];
            acc_dot += a4.x * s4.x + a4.y * s4.y + a4.z * s4.z + a4.w * s4.w;
        }
        float part = acc_dot * __expf(t0 - ti);
        if (lane < i) {
            part += alpha[(size_t)row * D + d_lds[lane]] * __expf(t_lds[lane] - ti);
        }
#pragma unroll
        for (int off = 32; off > 0; off >>= 1) part += __shfl_xor(part, off);
        if (lane == 0) {
            ll_acc += __logf(mu_r + part + EPSLOG);
            comp_acc += cs_r * (1.0f - __expf(ti - TMAXV));
        }
    }
    if (lane == 0) {
        red[wave] = ll_acc;
        red[4 + wave] = comp_acc;
    }
    __syncthreads();
    if (t == 0) {
        llp[blockIdx.x] = red[0] + red[1] + red[2] + red[3];
        compp[blockIdx.x] = red[4] + red[5] + red[6] + red[7];
    }
}

// final: out = sum(llp) - (T*sum(mu) + sum(compp)). 1 block, 1024 threads.
__global__ void k_final(const float* __restrict__ llp, const float* __restrict__ compp,
                        const float* __restrict__ mu, float* __restrict__ out) {
    __shared__ float r_ll[1024], r_cm[1024], r_mu[1024];
    int t = threadIdx.x;
    r_ll[t] = llp[t] + llp[t + 1024];
    r_cm[t] = compp[t] + compp[t + 1024];
    r_mu[t] = mu[t];
    __syncthreads();
    for (int off = 512; off > 0; off >>= 1) {
        if (t < off) {
            r_ll[t] += r_ll[t + off];
            r_cm[t] += r_cm[t + off];
            r_mu[t] += r_mu[t + off];
        }
        __syncthreads();
    }
    if (t == 0) out[0] = r_ll[0] - (TMAXV * r_mu[0] + r_cm[0]);
}

extern "C" void kernel_launch(void* const* d_in, const int* in_sizes, int n_in,
                              void* d_out, int out_size, void* d_ws, size_t ws_size,
                              hipStream_t stream) {
    const float* t_ev = (const float*)d_in[0];
    const int* marks = (const int*)d_in[1];
    const float* log_mu = (const float*)d_in[2];
    const float* log_alpha = (const float*)d_in[3];
    float* out = (float*)d_out;

    float* w = (float*)d_ws;
    float* alpha = w;                       // D*D
    float* Sl = alpha + (size_t)D * D;      // NC*D
    float* mu = Sl + (size_t)NC * D;        // D
    float* colsum = mu + D;                 // D
    float* llp = colsum + D;                // NB
    float* compp = llp + NB;                // NB
    float* A = compp + NB;                  // NG*D
    float* Sg = A + (size_t)NG * D;         // NG*D
    float* cumdec = Sg + (size_t)NG * D;    // NC

    k1<<<337, 256, 0, stream>>>(t_ev, marks, log_alpha, log_mu, alpha, mu, colsum, Sl, A);
    k_scanB<<<1, 1024, 0, stream>>>(t_ev, A, Sg, cumdec);
    k_main<<<NB, 256, 0, stream>>>(t_ev, marks, alpha, mu, colsum, Sl, Sg, cumdec, llp, compp);
    k_final<<<1, 1024, 0, stream>>>(llp, compp, mu, out);
}

// Round 8
// 114.519 us; speedup vs baseline: 1.8907x; 1.8907x over previous
//
#include <hip/hip_runtime.h>

// Hawkes log-likelihood, D=1024 dims, M=32768 events, BETA=1.
//
// lam_i = mu[d_i] + sum_{j<i} alpha[d_i,d_j] * exp(t_j - t_i).
// Chunk events into NC=512 chunks of C=64:
//   cross-chunk: exp(t_c0 - t_i) * dot(alpha[d_i,:], S_c)
//   in-chunk:    one lane-parallel predicated gather step (C == wave size)
// S_c via TWO-LEVEL dimension-parallel scan; level-1 histogram+scan fused in
// LDS (k_fused); level-2 fixup S = Sl + Sg*cumdec fused into k_main's S load.
// Compensator: sum_i colsum[d_i] * (1 - exp(t_i - T)) fused into k_main.
//
// Lessons: R2 — same-cacheline global atomics serialize (~15ns) -> zero
// global atomics. R5 — single-block LDS-atomic histogram = 43us on one CU.
// R6 — merging roles into one kernel pessimized regalloc (VGPR=20) and a
// 256-deep dependent load+softplus chain ran unpipelined = 135us straggler.
// => This version: R4's verified split pipeline + R5's verified k_fused.
// (R7 was an infra failure — container died — resubmitting unchanged.)
//
// ws floats: alpha[D*D] | Sl[NC*D] | mu[D] | colsum[D] | llp[NB] |
//            compp[NB] | A[NG*D] | Sg[NG*D] | cumdec[NC]   (~6.5 MB)
// P (colsum partials, 256*D) ALIASES Sl: P is dead before k_fused writes Sl.

#define D 1024
#define M 32768
#define C 64
#define NC (M / C)   /* 512 */
#define NB (NC * 4)  /* k_main blocks: 2048 */
#define NG 16        /* scan groups */
#define GC (NC / NG) /* 32 chunks per group */
#define TMAXV 1000.0f
#define EPSMU 1e-6f
#define EPSLOG 1e-8f

__device__ __forceinline__ float softplus(float x) {
    return (x > 0.0f) ? (x + log1pf(__expf(-x))) : log1pf(__expf(x));
}

// blocks 0..255: softplus(alpha) tile (4 rows x 1024 cols) + per-block colsum
// partial (plain store, no atomics). block 256: mu = softplus(log_mu) + eps.
__global__ void k_prep(const float* __restrict__ log_alpha, const float* __restrict__ log_mu,
                       float* __restrict__ alpha, float* __restrict__ mu,
                       float* __restrict__ P) {
    int t = threadIdx.x;
    int b = blockIdx.x;
    if (b < 256) {
        int r0 = b * 4;
        float cs[4] = {0.f, 0.f, 0.f, 0.f};
        for (int r = 0; r < 4; ++r) {
            size_t base = (size_t)(r0 + r) * D;
#pragma unroll
            for (int q = 0; q < 4; ++q) {
                int col = t + 256 * q;
                float a = softplus(log_alpha[base + col]);
                alpha[base + col] = a;
                cs[q] += a;
            }
        }
#pragma unroll
        for (int q = 0; q < 4; ++q) P[(size_t)b * D + t + 256 * q] = cs[q];
    } else {
#pragma unroll
        for (int q = 0; q < 4; ++q) {
            int k = t + 256 * q;
            mu[k] = softplus(log_mu[k]) + EPSMU;
        }
    }
}

// reduce P[256][D] -> colsum[D]; 4 blocks x 256 threads, one column each
__global__ void k_colred(const float* __restrict__ P, float* __restrict__ colsum) {
    int col = blockIdx.x * 256 + threadIdx.x;
    float s = 0.0f;
#pragma unroll 8
    for (int r = 0; r < 256; ++r) s += P[(size_t)r * D + col];
    colsum[col] = s;
}

// Fused level-1: per-chunk histograms built in LDS, scanned in LDS.
// 64 blocks = 16 groups x 4 dim-slices of 256. Writes local prefix Sl and
// group aggregate A. Lh referenced at next chunk's start time.
__global__ void k_fused(const float* __restrict__ t_ev, const int* __restrict__ marks,
                        float* __restrict__ Sl, float* __restrict__ A) {
    __shared__ float Lh[GC * 256];  // 32 KB
    __shared__ float dec[GC];
    __shared__ float tns[GC];
    int g = blockIdx.x >> 2, db = blockIdx.x & 3;
    int t = threadIdx.x;
#pragma unroll
    for (int q = 0; q < GC; ++q) Lh[q * 256 + t] = 0.0f;
    if (t < GC) {
        int gc = g * GC + t;
        float tn = (gc + 1 < NC) ? t_ev[(gc + 1) * C] : t_ev[M - 1];
        tns[t] = tn;
        dec[t] = (gc + 1 < NC) ? __expf(t_ev[gc * C] - tn) : 1.0f;
    }
    __syncthreads();
    int base = g * (GC * C);  // 2048 events per group
#pragma unroll
    for (int it = 0; it < 8; ++it) {
        int e = it * 256 + t;
        float te = t_ev[base + e];
        int m = marks[base + e];
        int lc = e >> 6;
        int ml = m - db * 256;
        if ((unsigned)ml < 256u) atomicAdd(&Lh[lc * 256 + ml], __expf(te - tns[lc]));
    }
    __syncthreads();
    int k = db * 256 + t;
    float S = 0.0f;
    for (int lc = 0; lc < GC; ++lc) {
        Sl[(size_t)(g * GC + lc) * D + k] = S;
        S = S * dec[lc] + Lh[lc * 256 + t];
    }
    A[(size_t)g * D + k] = S;
}

// Level-2 scan over the 16 group aggregates + per-chunk scalar cumdec.
__global__ void k_scanB(const float* __restrict__ t_ev, const float* __restrict__ A,
                        float* __restrict__ Sg, float* __restrict__ cumdec) {
    __shared__ float dec[NC];
    __shared__ float P[NG];
    int t = threadIdx.x;
    if (t < NC)
        dec[t] = (t + 1 < NC) ? __expf(t_ev[t * C] - t_ev[(t + 1) * C]) : 1.0f;
    __syncthreads();
    if (t < NC) {
        int g = t >> 5, r = t & 31;
        float p = 1.0f;
        for (int j = 0; j < r; ++j) p *= dec[g * GC + j];
        cumdec[t] = p;
        if (r == GC - 1) P[g] = p * dec[t];
    }
    __syncthreads();
    float a[NG];
#pragma unroll
    for (int g2 = 0; g2 < NG; ++g2) a[g2] = A[(size_t)g2 * D + t];
    float S = 0.0f;
#pragma unroll
    for (int g2 = 0; g2 < NG; ++g2) {
        Sg[(size_t)g2 * D + t] = S;
        S = S * P[g2] + a[g2];
    }
}

// main: 4 blocks per chunk (16 events each), fused scan fixup + compensator.
// Per-block partials, no global atomics.
__launch_bounds__(256)
__global__ void k_main(const float* __restrict__ t_ev, const int* __restrict__ marks,
                       const float* __restrict__ alpha, const float* __restrict__ mu,
                       const float* __restrict__ colsum, const float* __restrict__ Sl,
                       const float* __restrict__ Sg, const float* __restrict__ cumdec,
                       float* __restrict__ llp, float* __restrict__ compp) {
    __shared__ float S_lds[D];
    __shared__ float t_lds[C];
    __shared__ int d_lds[C];
    __shared__ float red[8];
    int t = threadIdx.x;
    int c = blockIdx.x >> 2, sub = blockIdx.x & 3;
    int g = c >> 5;
    float cd = cumdec[c];
#pragma unroll
    for (int q = 0; q < 4; ++q) {
        int k = t + 256 * q;
        S_lds[k] = Sl[(size_t)c * D + k] + Sg[(size_t)g * D + k] * cd;
    }
    if (t < C) {
        t_lds[t] = t_ev[c * C + t];
        d_lds[t] = marks[c * C + t];
    }
    __syncthreads();
    int wave = t >> 6, lane = t & 63;
    float t0 = t_lds[0];
    float ll_acc = 0.0f, comp_acc = 0.0f;
    for (int i = sub * 16 + wave; i < sub * 16 + 16; i += 4) {
        int row = d_lds[i];
        float ti = t_lds[i];
        float mu_r = mu[row];
        float cs_r = colsum[row];
        const float4* arow = (const float4*)(alpha + (size_t)row * D);
        const float4* srow = (const float4*)S_lds;
        float acc_dot = 0.0f;
#pragma unroll
        for (int u = 0; u < 4; ++u) {
            float4 a4 = arow[lane + 64 * u];
            float4 s4 = srow[lane + 64 * u];
            acc_dot += a4.x * s4.x + a4.y * s4.y + a4.z * s4.z + a4.w * s4.w;
        }
        float part = acc_dot * __expf(t0 - ti);
        if (lane < i) {
            part += alpha[(size_t)row * D + d_lds[lane]] * __expf(t_lds[lane] - ti);
        }
#pragma unroll
        for (int off = 32; off > 0; off >>= 1) part += __shfl_xor(part, off);
        if (lane == 0) {
            ll_acc += __logf(mu_r + part + EPSLOG);
            comp_acc += cs_r * (1.0f - __expf(ti - TMAXV));
        }
    }
    if (lane == 0) {
        red[wave] = ll_acc;
        red[4 + wave] = comp_acc;
    }
    __syncthreads();
    if (t == 0) {
        llp[blockIdx.x] = red[0] + red[1] + red[2] + red[3];
        compp[blockIdx.x] = red[4] + red[5] + red[6] + red[7];
    }
}

// final: out = sum(llp) - (T*sum(mu) + sum(compp)). 1 block, 1024 threads.
__global__ void k_final(const float* __restrict__ llp, const float* __restrict__ compp,
                        const float* __restrict__ mu, float* __restrict__ out) {
    __shared__ float r_ll[1024], r_cm[1024], r_mu[1024];
    int t = threadIdx.x;
    r_ll[t] = llp[t] + llp[t + 1024];
    r_cm[t] = compp[t] + compp[t + 1024];
    r_mu[t] = mu[t];
    __syncthreads();
    for (int off = 512; off > 0; off >>= 1) {
        if (t < off) {
            r_ll[t] += r_ll[t + off];
            r_cm[t] += r_cm[t + off];
            r_mu[t] += r_mu[t + off];
        }
        __syncthreads();
    }
    if (t == 0) out[0] = r_ll[0] - (TMAXV * r_mu[0] + r_cm[0]);
}

extern "C" void kernel_launch(void* const* d_in, const int* in_sizes, int n_in,
                              void* d_out, int out_size, void* d_ws, size_t ws_size,
                              hipStream_t stream) {
    const float* t_ev = (const float*)d_in[0];
    const int* marks = (const int*)d_in[1];
    const float* log_mu = (const float*)d_in[2];
    const float* log_alpha = (const float*)d_in[3];
    float* out = (float*)d_out;

    float* w = (float*)d_ws;
    float* alpha = w;                       // D*D
    float* Sl = alpha + (size_t)D * D;      // NC*D
    float* mu = Sl + (size_t)NC * D;        // D
    float* colsum = mu + D;                 // D
    float* llp = colsum + D;                // NB
    float* compp = llp + NB;                // NB
    float* A = compp + NB;                  // NG*D
    float* Sg = A + (size_t)NG * D;         // NG*D
    float* cumdec = Sg + (size_t)NG * D;    // NC
    float* P = Sl;                          // ALIAS: dead before k_fused writes Sl

    k_prep<<<257, 256, 0, stream>>>(log_alpha, log_mu, alpha, mu, P);
    k_colred<<<4, 256, 0, stream>>>(P, colsum);
    k_fused<<<64, 256, 0, stream>>>(t_ev, marks, Sl, A);
    k_scanB<<<1, 1024, 0, stream>>>(t_ev, A, Sg, cumdec);
    k_main<<<NB, 256, 0, stream>>>(t_ev, marks, alpha, mu, colsum, Sl, Sg, cumdec, llp, compp);
    k_final<<<1, 1024, 0, stream>>>(llp, compp, mu, out);
}

// Round 9
// 103.075 us; speedup vs baseline: 2.1006x; 1.1110x over previous
//
#include <hip/hip_runtime.h>

// Hawkes log-likelihood, D=1024 dims, M=32768 events, BETA=1.
//
// lam_i = mu[d_i] + sum_{j<i} alpha[d_i,d_j] * exp(t_j - t_i).
// Chunk events into NC=512 chunks of C=64:
//   cross-chunk: exp(t_c0 - t_i) * dot(alpha[d_i,:], S_c)
//   in-chunk:    one lane-parallel predicated gather step (C == wave size)
// S_c via TWO-LEVEL dimension-parallel scan; level-1 histogram+scan fused in
// LDS (k_fused); level-2 fixup S = Sl + Sg*cumdec fused into k_main's S load.
// Compensator: sum_i colsum[d_i] * (1 - exp(t_i - T)) fused into k_main.
//
// Lessons: R2 — same-cacheline global atomics serialize (~15ns) -> zero
// global atomics. R5 — single-block LDS-atomic histogram = 43us on one CU.
// R6 — merging roles into one kernel pessimized regalloc; dependent strided
// load chains must stay in their own kernel. R8 — k_colred at 4 blocks was
// ~15us (cross-XCD L2 misses, unpipelined): widened to 32 blocks here.
//
// ws floats: alpha[D*D] | Sl[NC*D] | mu[D] | colsum[D] | llp[NB] |
//            compp[NB] | A[NG*D] | Sg[NG*D] | cumdec[NC]   (~6.5 MB)
// P (colsum partials, 256*D) ALIASES Sl: P is dead before k_fused writes Sl.

#define D 1024
#define M 32768
#define C 64
#define NC (M / C)   /* 512 */
#define NB (NC * 4)  /* k_main blocks: 2048 */
#define NG 16        /* scan groups */
#define GC (NC / NG) /* 32 chunks per group */
#define TMAXV 1000.0f
#define EPSMU 1e-6f
#define EPSLOG 1e-8f

__device__ __forceinline__ float softplus(float x) {
    return (x > 0.0f) ? (x + log1pf(__expf(-x))) : log1pf(__expf(x));
}

// blocks 0..255: softplus(alpha) tile (4 rows x 1024 cols) + per-block colsum
// partial (plain store, no atomics). block 256: mu = softplus(log_mu) + eps.
__global__ void k_prep(const float* __restrict__ log_alpha, const float* __restrict__ log_mu,
                       float* __restrict__ alpha, float* __restrict__ mu,
                       float* __restrict__ P) {
    int t = threadIdx.x;
    int b = blockIdx.x;
    if (b < 256) {
        int r0 = b * 4;
        float cs[4] = {0.f, 0.f, 0.f, 0.f};
        for (int r = 0; r < 4; ++r) {
            size_t base = (size_t)(r0 + r) * D;
#pragma unroll
            for (int q = 0; q < 4; ++q) {
                int col = t + 256 * q;
                float a = softplus(log_alpha[base + col]);
                alpha[base + col] = a;
                cs[q] += a;
            }
        }
#pragma unroll
        for (int q = 0; q < 4; ++q) P[(size_t)b * D + t + 256 * q] = cs[q];
    } else {
#pragma unroll
        for (int q = 0; q < 4; ++q) {
            int k = t + 256 * q;
            mu[k] = softplus(log_mu[k]) + EPSMU;
        }
    }
}

// reduce P[256][D] -> colsum[D]; 32 blocks x 256 threads, 32 cols/block.
// 8 row-segments of 32 rows each, coalesced across lanes, LDS combine.
__global__ void k_colred(const float* __restrict__ P, float* __restrict__ colsum) {
    __shared__ float red[8][32];
    int t = threadIdx.x;
    int colL = t & 31, seg = t >> 5;  // 8 segs x 32 cols
    int col = blockIdx.x * 32 + colL;
    float s = 0.0f;
#pragma unroll 8
    for (int j = 0; j < 32; ++j)
        s += P[(size_t)(seg * 32 + j) * D + col];
    red[seg][colL] = s;
    __syncthreads();
    if (t < 32) {
        float v = 0.0f;
#pragma unroll
        for (int k = 0; k < 8; ++k) v += red[k][t];
        colsum[blockIdx.x * 32 + t] = v;
    }
}

// Fused level-1: per-chunk histograms built in LDS, scanned in LDS.
// 64 blocks = 16 groups x 4 dim-slices of 256. Writes local prefix Sl and
// group aggregate A. Lh referenced at next chunk's start time.
__global__ void k_fused(const float* __restrict__ t_ev, const int* __restrict__ marks,
                        float* __restrict__ Sl, float* __restrict__ A) {
    __shared__ float Lh[GC * 256];  // 32 KB
    __shared__ float dec[GC];
    __shared__ float tns[GC];
    int g = blockIdx.x >> 2, db = blockIdx.x & 3;
    int t = threadIdx.x;
#pragma unroll
    for (int q = 0; q < GC; ++q) Lh[q * 256 + t] = 0.0f;
    if (t < GC) {
        int gc = g * GC + t;
        float tn = (gc + 1 < NC) ? t_ev[(gc + 1) * C] : t_ev[M - 1];
        tns[t] = tn;
        dec[t] = (gc + 1 < NC) ? __expf(t_ev[gc * C] - tn) : 1.0f;
    }
    __syncthreads();
    int base = g * (GC * C);  // 2048 events per group
#pragma unroll
    for (int it = 0; it < 8; ++it) {
        int e = it * 256 + t;
        float te = t_ev[base + e];
        int m = marks[base + e];
        int lc = e >> 6;
        int ml = m - db * 256;
        if ((unsigned)ml < 256u) atomicAdd(&Lh[lc * 256 + ml], __expf(te - tns[lc]));
    }
    __syncthreads();
    int k = db * 256 + t;
    float S = 0.0f;
    for (int lc = 0; lc < GC; ++lc) {
        Sl[(size_t)(g * GC + lc) * D + k] = S;
        S = S * dec[lc] + Lh[lc * 256 + t];
    }
    A[(size_t)g * D + k] = S;
}

// Level-2 scan over the 16 group aggregates + per-chunk scalar cumdec.
__global__ void k_scanB(const float* __restrict__ t_ev, const float* __restrict__ A,
                        float* __restrict__ Sg, float* __restrict__ cumdec) {
    __shared__ float dec[NC];
    __shared__ float P[NG];
    int t = threadIdx.x;
    if (t < NC)
        dec[t] = (t + 1 < NC) ? __expf(t_ev[t * C] - t_ev[(t + 1) * C]) : 1.0f;
    __syncthreads();
    if (t < NC) {
        int g = t >> 5, r = t & 31;
        float p = 1.0f;
        for (int j = 0; j < r; ++j) p *= dec[g * GC + j];
        cumdec[t] = p;
        if (r == GC - 1) P[g] = p * dec[t];
    }
    __syncthreads();
    float a[NG];
#pragma unroll
    for (int g2 = 0; g2 < NG; ++g2) a[g2] = A[(size_t)g2 * D + t];
    float S = 0.0f;
#pragma unroll
    for (int g2 = 0; g2 < NG; ++g2) {
        Sg[(size_t)g2 * D + t] = S;
        S = S * P[g2] + a[g2];
    }
}

// main: 4 blocks per chunk (16 events each), fused scan fixup + compensator.
// Per-block partials, no global atomics.
__launch_bounds__(256)
__global__ void k_main(const float* __restrict__ t_ev, const int* __restrict__ marks,
                       const float* __restrict__ alpha, const float* __restrict__ mu,
                       const float* __restrict__ colsum, const float* __restrict__ Sl,
                       const float* __restrict__ Sg, const float* __restrict__ cumdec,
                       float* __restrict__ llp, float* __restrict__ compp) {
    __shared__ float S_lds[D];
    __shared__ float t_lds[C];
    __shared__ int d_lds[C];
    __shared__ float red[8];
    int t = threadIdx.x;
    int c = blockIdx.x >> 2, sub = blockIdx.x & 3;
    int g = c >> 5;
    float cd = cumdec[c];
#pragma unroll
    for (int q = 0; q < 4; ++q) {
        int k = t + 256 * q;
        S_lds[k] = Sl[(size_t)c * D + k] + Sg[(size_t)g * D + k] * cd;
    }
    if (t < C) {
        t_lds[t] = t_ev[c * C + t];
        d_lds[t] = marks[c * C + t];
    }
    __syncthreads();
    int wave = t >> 6, lane = t & 63;
    float t0 = t_lds[0];
    float ll_acc = 0.0f, comp_acc = 0.0f;
    for (int i = sub * 16 + wave; i < sub * 16 + 16; i += 4) {
        int row = d_lds[i];
        float ti = t_lds[i];
        float mu_r = mu[row];
        float cs_r = colsum[row];
        const float4* arow = (const float4*)(alpha + (size_t)row * D);
        const float4* srow = (const float4*)S_lds;
        float acc_dot = 0.0f;
#pragma unroll
        for (int u = 0; u < 4; ++u) {
            float4 a4 = arow[lane + 64 * u];
            float4 s4 = srow[lane + 64 * u];
            acc_dot += a4.x * s4.x + a4.y * s4.y + a4.z * s4.z + a4.w * s4.w;
        }
        float part = acc_dot * __expf(t0 - ti);
        if (lane < i) {
            part += alpha[(size_t)row * D + d_lds[lane]] * __expf(t_lds[lane] - ti);
        }
#pragma unroll
        for (int off = 32; off > 0; off >>= 1) part += __shfl_xor(part, off);
        if (lane == 0) {
            ll_acc += __logf(mu_r + part + EPSLOG);
            comp_acc += cs_r * (1.0f - __expf(ti - TMAXV));
        }
    }
    if (lane == 0) {
        red[wave] = ll_acc;
        red[4 + wave] = comp_acc;
    }
    __syncthreads();
    if (t == 0) {
        llp[blockIdx.x] = red[0] + red[1] + red[2] + red[3];
        compp[blockIdx.x] = red[4] + red[5] + red[6] + red[7];
    }
}

// final: out = sum(llp) - (T*sum(mu) + sum(compp)). 1 block, 1024 threads.
__global__ void k_final(const float* __restrict__ llp, const float* __restrict__ compp,
                        const float* __restrict__ mu, float* __restrict__ out) {
    __shared__ float r_ll[1024], r_cm[1024], r_mu[1024];
    int t = threadIdx.x;
    r_ll[t] = llp[t] + llp[t + 1024];
    r_cm[t] = compp[t] + compp[t + 1024];
    r_mu[t] = mu[t];
    __syncthreads();
    for (int off = 512; off > 0; off >>= 1) {
        if (t < off) {
            r_ll[t] += r_ll[t + off];
            r_cm[t] += r_cm[t + off];
            r_mu[t] += r_mu[t + off];
        }
        __syncthreads();
    }
    if (t == 0) out[0] = r_ll[0] - (TMAXV * r_mu[0] + r_cm[0]);
}

extern "C" void kernel_launch(void* const* d_in, const int* in_sizes, int n_in,
                              void* d_out, int out_size, void* d_ws, size_t ws_size,
                              hipStream_t stream) {
    const float* t_ev = (const float*)d_in[0];
    const int* marks = (const int*)d_in[1];
    const float* log_mu = (const float*)d_in[2];
    const float* log_alpha = (const float*)d_in[3];
    float* out = (float*)d_out;

    float* w = (float*)d_ws;
    float* alpha = w;                       // D*D
    float* Sl = alpha + (size_t)D * D;      // NC*D
    float* mu = Sl + (size_t)NC * D;        // D
    float* colsum = mu + D;                 // D
    float* llp = colsum + D;                // NB
    float* compp = llp + NB;                // NB
    float* A = compp + NB;                  // NG*D
    float* Sg = A + (size_t)NG * D;         // NG*D
    float* cumdec = Sg + (size_t)NG * D;    // NC
    float* P = Sl;                          // ALIAS: dead before k_fused writes Sl

    k_prep<<<257, 256, 0, stream>>>(log_alpha, log_mu, alpha, mu, P);
    k_colred<<<32, 256, 0, stream>>>(P, colsum);
    k_fused<<<64, 256, 0, stream>>>(t_ev, marks, Sl, A);
    k_scanB<<<1, 1024, 0, stream>>>(t_ev, A, Sg, cumdec);
    k_main<<<NB, 256, 0, stream>>>(t_ev, marks, alpha, mu, colsum, Sl, Sg, cumdec, llp, compp);
    k_final<<<1, 1024, 0, stream>>>(llp, compp, mu, out);
}

// Round 10
// 98.537 us; speedup vs baseline: 2.1973x; 1.0461x over previous
//
#include <hip/hip_runtime.h>

// Hawkes log-likelihood, D=1024 dims, M=32768 events, BETA=1.
//
// lam_i = mu[d_i] + sum_{j<i} alpha[d_i,d_j] * exp(t_j - t_i).
// Chunk events into NC=512 chunks of C=64:
//   cross-chunk: exp(t_c0 - t_i) * dot(alpha[d_i,:], S_c)
//   in-chunk:    one lane-parallel predicated gather step (C == wave size)
// S_c via TWO-LEVEL dimension-parallel scan; level-1 histogram+scan fused in
// LDS (k_fused); level-2 fixup S = Sl + Sg*cumdec fused into k_main's S load.
// Compensator: sum_i colsum[d_i] * (1 - exp(t_i - T)) fused into k_main.
//
// Lessons: R2 — same-cacheline global atomics serialize -> zero global
// atomics. R5 — single-block LDS-atomic histogram = 43us on one CU. R6 —
// merged-role kernels can pessimize regalloc; keep dependent-chain kernels
// separate. R8/R9 — k_colred at 32 blocks (verified -11us). R10 — alpha
// stored as BF16 for the dot path (halves k_main L2 traffic + k_prep
// stores); colsum/compensator stays fp32 via P partials, so only the
// log-damped dot sees the 0.2% bf16 error (abs ~1e2 vs 1.35e4 threshold).
//
// ws: ab(bf16)[D*D] | Sl[NC*D] | mu[D] | colsum[D] | llp[NB] | compp[NB] |
//     A[NG*D] | Sg[NG*D] | cumdec[NC]   (~5.5 MB)
// P (colsum partials fp32, 256*D) ALIASES Sl: dead before k_fused writes Sl.

#define D 1024
#define M 32768
#define C 64
#define NC (M / C)   /* 512 */
#define NB (NC * 4)  /* k_main blocks: 2048 */
#define NG 16        /* scan groups */
#define GC (NC / NG) /* 32 chunks per group */
#define TMAXV 1000.0f
#define EPSMU 1e-6f
#define EPSLOG 1e-8f

__device__ __forceinline__ float softplus(float x) {
    return (x > 0.0f) ? (x + log1pf(__expf(-x))) : log1pf(__expf(x));
}

// round-to-nearest-even fp32 -> bf16 (inputs are positive finite)
__device__ __forceinline__ unsigned short f2bf(float x) {
    unsigned u = __float_as_uint(x);
    return (unsigned short)((u + 0x7FFFu + ((u >> 16) & 1u)) >> 16);
}
__device__ __forceinline__ float bf2f(unsigned short h) {
    return __uint_as_float(((unsigned)h) << 16);
}

// blocks 0..255: softplus(alpha) tile (4 rows x 1024 cols) -> bf16 store +
// per-block fp32 colsum partial. block 256: mu = softplus(log_mu) + eps.
__global__ void k_prep(const float* __restrict__ log_alpha, const float* __restrict__ log_mu,
                       unsigned short* __restrict__ ab, float* __restrict__ mu,
                       float* __restrict__ P) {
    int t = threadIdx.x;
    int b = blockIdx.x;
    if (b < 256) {
        int r0 = b * 4;
        float4 cs = {0.f, 0.f, 0.f, 0.f};
        for (int r = 0; r < 4; ++r) {
            const float4* src = (const float4*)(log_alpha + (size_t)(r0 + r) * D);
            float4 v = src[t];
            float4 a;
            a.x = softplus(v.x);
            a.y = softplus(v.y);
            a.z = softplus(v.z);
            a.w = softplus(v.w);
            cs.x += a.x; cs.y += a.y; cs.z += a.z; cs.w += a.w;
            ushort4 h;
            h.x = f2bf(a.x); h.y = f2bf(a.y); h.z = f2bf(a.z); h.w = f2bf(a.w);
            ((ushort4*)(ab + (size_t)(r0 + r) * D))[t] = h;
        }
        ((float4*)(P + (size_t)b * D))[t] = cs;  // P[b][col], col = 4t+j
    } else {
#pragma unroll
        for (int q = 0; q < 4; ++q) {
            int k = t + 256 * q;
            mu[k] = softplus(log_mu[k]) + EPSMU;
        }
    }
}

// reduce P[256][D] -> colsum[D]; 32 blocks x 256 threads, 32 cols/block.
__global__ void k_colred(const float* __restrict__ P, float* __restrict__ colsum) {
    __shared__ float red[8][32];
    int t = threadIdx.x;
    int colL = t & 31, seg = t >> 5;  // 8 segs x 32 cols
    int col = blockIdx.x * 32 + colL;
    float s = 0.0f;
#pragma unroll 8
    for (int j = 0; j < 32; ++j)
        s += P[(size_t)(seg * 32 + j) * D + col];
    red[seg][colL] = s;
    __syncthreads();
    if (t < 32) {
        float v = 0.0f;
#pragma unroll
        for (int k = 0; k < 8; ++k) v += red[k][t];
        colsum[blockIdx.x * 32 + t] = v;
    }
}

// Fused level-1: per-chunk histograms built in LDS, scanned in LDS.
// 64 blocks = 16 groups x 4 dim-slices of 256.
__global__ void k_fused(const float* __restrict__ t_ev, const int* __restrict__ marks,
                        float* __restrict__ Sl, float* __restrict__ A) {
    __shared__ float Lh[GC * 256];  // 32 KB
    __shared__ float dec[GC];
    __shared__ float tns[GC];
    int g = blockIdx.x >> 2, db = blockIdx.x & 3;
    int t = threadIdx.x;
#pragma unroll
    for (int q = 0; q < GC; ++q) Lh[q * 256 + t] = 0.0f;
    if (t < GC) {
        int gc = g * GC + t;
        float tn = (gc + 1 < NC) ? t_ev[(gc + 1) * C] : t_ev[M - 1];
        tns[t] = tn;
        dec[t] = (gc + 1 < NC) ? __expf(t_ev[gc * C] - tn) : 1.0f;
    }
    __syncthreads();
    int base = g * (GC * C);  // 2048 events per group
#pragma unroll
    for (int it = 0; it < 8; ++it) {
        int e = it * 256 + t;
        float te = t_ev[base + e];
        int m = marks[base + e];
        int lc = e >> 6;
        int ml = m - db * 256;
        if ((unsigned)ml < 256u) atomicAdd(&Lh[lc * 256 + ml], __expf(te - tns[lc]));
    }
    __syncthreads();
    int k = db * 256 + t;
    float S = 0.0f;
    for (int lc = 0; lc < GC; ++lc) {
        Sl[(size_t)(g * GC + lc) * D + k] = S;
        S = S * dec[lc] + Lh[lc * 256 + t];
    }
    A[(size_t)g * D + k] = S;
}

// Level-2 scan over the 16 group aggregates + per-chunk scalar cumdec.
__global__ void k_scanB(const float* __restrict__ t_ev, const float* __restrict__ A,
                        float* __restrict__ Sg, float* __restrict__ cumdec) {
    __shared__ float dec[NC];
    __shared__ float P[NG];
    int t = threadIdx.x;
    if (t < NC)
        dec[t] = (t + 1 < NC) ? __expf(t_ev[t * C] - t_ev[(t + 1) * C]) : 1.0f;
    __syncthreads();
    if (t < NC) {
        int g = t >> 5, r = t & 31;
        float p = 1.0f;
        for (int j = 0; j < r; ++j) p *= dec[g * GC + j];
        cumdec[t] = p;
        if (r == GC - 1) P[g] = p * dec[t];
    }
    __syncthreads();
    float a[NG];
#pragma unroll
    for (int g2 = 0; g2 < NG; ++g2) a[g2] = A[(size_t)g2 * D + t];
    float S = 0.0f;
#pragma unroll
    for (int g2 = 0; g2 < NG; ++g2) {
        Sg[(size_t)g2 * D + t] = S;
        S = S * P[g2] + a[g2];
    }
}

// main: 4 blocks per chunk (16 events each), fused scan fixup + compensator.
// alpha read as bf16 (8 per uint4, lane covers 16 consecutive cols).
__launch_bounds__(256)
__global__ void k_main(const float* __restrict__ t_ev, const int* __restrict__ marks,
                       const unsigned short* __restrict__ ab, const float* __restrict__ mu,
                       const float* __restrict__ colsum, const float* __restrict__ Sl,
                       const float* __restrict__ Sg, const float* __restrict__ cumdec,
                       float* __restrict__ llp, float* __restrict__ compp) {
    __shared__ float S_lds[D];
    __shared__ float t_lds[C];
    __shared__ int d_lds[C];
    __shared__ float red[8];
    int t = threadIdx.x;
    int c = blockIdx.x >> 2, sub = blockIdx.x & 3;
    int g = c >> 5;
    float cd = cumdec[c];
#pragma unroll
    for (int q = 0; q < 4; ++q) {
        int k = t + 256 * q;
        S_lds[k] = Sl[(size_t)c * D + k] + Sg[(size_t)g * D + k] * cd;
    }
    if (t < C) {
        t_lds[t] = t_ev[c * C + t];
        d_lds[t] = marks[c * C + t];
    }
    __syncthreads();
    int wave = t >> 6, lane = t & 63;
    float t0 = t_lds[0];
    float ll_acc = 0.0f, comp_acc = 0.0f;
    for (int i = sub * 16 + wave; i < sub * 16 + 16; i += 4) {
        int row = d_lds[i];
        float ti = t_lds[i];
        float mu_r = mu[row];
        float cs_r = colsum[row];
        const uint4* arow = (const uint4*)(ab + (size_t)row * D);
        float acc_dot = 0.0f;
#pragma unroll
        for (int u = 0; u < 2; ++u) {
            uint4 pk = arow[2 * lane + u];  // 8 bf16: cols 16*lane+8u .. +7
            const float4* sp = (const float4*)(S_lds + 16 * lane + 8 * u);
            float4 s0 = sp[0], s1 = sp[1];
            acc_dot += __uint_as_float(pk.x << 16) * s0.x
                     + __uint_as_float(pk.x & 0xFFFF0000u) * s0.y
                     + __uint_as_float(pk.y << 16) * s0.z
                     + __uint_as_float(pk.y & 0xFFFF0000u) * s0.w
                     + __uint_as_float(pk.z << 16) * s1.x
                     + __uint_as_float(pk.z & 0xFFFF0000u) * s1.y
                     + __uint_as_float(pk.w << 16) * s1.z
                     + __uint_as_float(pk.w & 0xFFFF0000u) * s1.w;
        }
        float part = acc_dot * __expf(t0 - ti);
        if (lane < i) {
            part += bf2f(ab[(size_t)row * D + d_lds[lane]]) * __expf(t_lds[lane] - ti);
        }
#pragma unroll
        for (int off = 32; off > 0; off >>= 1) part += __shfl_xor(part, off);
        if (lane == 0) {
            ll_acc += __logf(mu_r + part + EPSLOG);
            comp_acc += cs_r * (1.0f - __expf(ti - TMAXV));
        }
    }
    if (lane == 0) {
        red[wave] = ll_acc;
        red[4 + wave] = comp_acc;
    }
    __syncthreads();
    if (t == 0) {
        llp[blockIdx.x] = red[0] + red[1] + red[2] + red[3];
        compp[blockIdx.x] = red[4] + red[5] + red[6] + red[7];
    }
}

// final: out = sum(llp) - (T*sum(mu) + sum(compp)). 1 block, 1024 threads.
__global__ void k_final(const float* __restrict__ llp, const float* __restrict__ compp,
                        const float* __restrict__ mu, float* __restrict__ out) {
    __shared__ float r_ll[1024], r_cm[1024], r_mu[1024];
    int t = threadIdx.x;
    r_ll[t] = llp[t] + llp[t + 1024];
    r_cm[t] = compp[t] + compp[t + 1024];
    r_mu[t] = mu[t];
    __syncthreads();
    for (int off = 512; off > 0; off >>= 1) {
        if (t < off) {
            r_ll[t] += r_ll[t + off];
            r_cm[t] += r_cm[t + off];
            r_mu[t] += r_mu[t + off];
        }
        __syncthreads();
    }
    if (t == 0) out[0] = r_ll[0] - (TMAXV * r_mu[0] + r_cm[0]);
}

extern "C" void kernel_launch(void* const* d_in, const int* in_sizes, int n_in,
                              void* d_out, int out_size, void* d_ws, size_t ws_size,
                              hipStream_t stream) {
    const float* t_ev = (const float*)d_in[0];
    const int* marks = (const int*)d_in[1];
    const float* log_mu = (const float*)d_in[2];
    const float* log_alpha = (const float*)d_in[3];
    float* out = (float*)d_out;

    float* w = (float*)d_ws;
    unsigned short* ab = (unsigned short*)w;        // D*D bf16 = D*D/2 floats
    float* Sl = w + (size_t)D * D / 2;              // NC*D
    float* mu = Sl + (size_t)NC * D;                // D
    float* colsum = mu + D;                         // D
    float* llp = colsum + D;                        // NB
    float* compp = llp + NB;                        // NB
    float* A = compp + NB;                          // NG*D
    float* Sg = A + (size_t)NG * D;                 // NG*D
    float* cumdec = Sg + (size_t)NG * D;            // NC
    float* P = Sl;                                  // ALIAS: dead before k_fused writes Sl

    k_prep<<<257, 256, 0, stream>>>(log_alpha, log_mu, ab, mu, P);
    k_colred<<<32, 256, 0, stream>>>(P, colsum);
    k_fused<<<64, 256, 0, stream>>>(t_ev, marks, Sl, A);
    k_scanB<<<1, 1024, 0, stream>>>(t_ev, A, Sg, cumdec);
    k_main<<<NB, 256, 0, stream>>>(t_ev, marks, ab, mu, colsum, Sl, Sg, cumdec, llp, compp);
    k_final<<<1, 1024, 0, stream>>>(llp, compp, mu, out);
}

// Round 11
// 94.032 us; speedup vs baseline: 2.3026x; 1.0479x over previous
//
#include <hip/hip_runtime.h>

// Hawkes log-likelihood, D=1024 dims, M=32768 events, BETA=1.
//
// lam_i = mu[d_i] + sum_{j<i} alpha[d_i,d_j] * exp(t_j - t_i).
// Chunk events into NC=512 chunks of C=64:
//   cross-chunk: exp(t_c0 - t_i) * dot(alpha[d_i,:], S_c)
//   in-chunk:    one lane-parallel predicated gather step (C == wave size)
// S_c via TWO-LEVEL dimension-parallel scan; level-1 histogram+scan fused in
// LDS (k_fused); level-2 fixup S = Sl + Sg*cumdec fused into k_main's S load.
// Compensator: sum_i colsum[d_i] * (1 - exp(t_i - T)) fused into k_main.
//
// Lessons: R2 — same-cacheline global atomics serialize -> zero global
// atomics (also why cooperative grid.sync was rejected). R5 — single-block
// LDS-atomic histogram = 43us on one CU. R6 — merged-role kernels with DEEP
// dependent chains pessimize regalloc; shallow reductions are safe to merge.
// R9 — wide colred. R10 — bf16 alpha for the dot path. R11 — k_main at 8
// blocks/chunk (2 events/wave, halved latency chain) + colred/scanB merged
// into k_mid (one fewer dispatch; P un-aliased, pipeline reordered).
//
// ws floats: ab(bf16)[D*D] | Sl[NC*D] | mu[D] | colsum[D] | P[256*D] |
//            llp[NB] | compp[NB] | A[NG*D] | Sg[NG*D] | cumdec[NC]  (~5.5MB)

#define D 1024
#define M 32768
#define C 64
#define NC (M / C)   /* 512 */
#define NB (NC * 8)  /* k_main blocks: 4096 */
#define NG 16        /* scan groups */
#define GC (NC / NG) /* 32 chunks per group */
#define TMAXV 1000.0f
#define EPSMU 1e-6f
#define EPSLOG 1e-8f

__device__ __forceinline__ float softplus(float x) {
    return (x > 0.0f) ? (x + log1pf(__expf(-x))) : log1pf(__expf(x));
}

// round-to-nearest-even fp32 -> bf16 (inputs are positive finite)
__device__ __forceinline__ unsigned short f2bf(float x) {
    unsigned u = __float_as_uint(x);
    return (unsigned short)((u + 0x7FFFu + ((u >> 16) & 1u)) >> 16);
}
__device__ __forceinline__ float bf2f(unsigned short h) {
    return __uint_as_float(((unsigned)h) << 16);
}

// blocks 0..255: softplus(alpha) tile (4 rows x 1024 cols) -> bf16 store +
// per-block fp32 colsum partial. block 256: mu = softplus(log_mu) + eps.
__global__ void k_prep(const float* __restrict__ log_alpha, const float* __restrict__ log_mu,
                       unsigned short* __restrict__ ab, float* __restrict__ mu,
                       float* __restrict__ P) {
    int t = threadIdx.x;
    int b = blockIdx.x;
    if (b < 256) {
        int r0 = b * 4;
        float4 cs = {0.f, 0.f, 0.f, 0.f};
        for (int r = 0; r < 4; ++r) {
            const float4* src = (const float4*)(log_alpha + (size_t)(r0 + r) * D);
            float4 v = src[t];
            float4 a;
            a.x = softplus(v.x);
            a.y = softplus(v.y);
            a.z = softplus(v.z);
            a.w = softplus(v.w);
            cs.x += a.x; cs.y += a.y; cs.z += a.z; cs.w += a.w;
            ushort4 h;
            h.x = f2bf(a.x); h.y = f2bf(a.y); h.z = f2bf(a.z); h.w = f2bf(a.w);
            ((ushort4*)(ab + (size_t)(r0 + r) * D))[t] = h;
        }
        ((float4*)(P + (size_t)b * D))[t] = cs;  // P[b][col], col = 4t+j
    } else {
#pragma unroll
        for (int q = 0; q < 4; ++q) {
            int k = t + 256 * q;
            mu[k] = softplus(log_mu[k]) + EPSMU;
        }
    }
}

// Fused level-1: per-chunk histograms built in LDS, scanned in LDS.
// 64 blocks = 16 groups x 4 dim-slices of 256.
__global__ void k_fused(const float* __restrict__ t_ev, const int* __restrict__ marks,
                        float* __restrict__ Sl, float* __restrict__ A) {
    __shared__ float Lh[GC * 256];  // 32 KB
    __shared__ float dec[GC];
    __shared__ float tns[GC];
    int g = blockIdx.x >> 2, db = blockIdx.x & 3;
    int t = threadIdx.x;
#pragma unroll
    for (int q = 0; q < GC; ++q) Lh[q * 256 + t] = 0.0f;
    if (t < GC) {
        int gc = g * GC + t;
        float tn = (gc + 1 < NC) ? t_ev[(gc + 1) * C] : t_ev[M - 1];
        tns[t] = tn;
        dec[t] = (gc + 1 < NC) ? __expf(t_ev[gc * C] - tn) : 1.0f;
    }
    __syncthreads();
    int base = g * (GC * C);  // 2048 events per group
#pragma unroll
    for (int it = 0; it < 8; ++it) {
        int e = it * 256 + t;
        float te = t_ev[base + e];
        int m = marks[base + e];
        int lc = e >> 6;
        int ml = m - db * 256;
        if ((unsigned)ml < 256u) atomicAdd(&Lh[lc * 256 + ml], __expf(te - tns[lc]));
    }
    __syncthreads();
    int k = db * 256 + t;
    float S = 0.0f;
    for (int lc = 0; lc < GC; ++lc) {
        Sl[(size_t)(g * GC + lc) * D + k] = S;
        S = S * dec[lc] + Lh[lc * 256 + t];
    }
    A[(size_t)g * D + k] = S;
}

// Merged mid-stage, 9 blocks x 1024 threads (both roles are SHALLOW):
//   blocks 0..7: reduce P[256][D] -> colsum (128 cols/block, 8 segs x 32 rows)
//   block 8:     level-2 scan over 16 group aggregates + per-chunk cumdec
__global__ void k_mid(const float* __restrict__ P, float* __restrict__ colsum,
                      const float* __restrict__ t_ev, const float* __restrict__ A,
                      float* __restrict__ Sg, float* __restrict__ cumdec) {
    int t = threadIdx.x;
    if (blockIdx.x < 8) {
        __shared__ float red[8][128];
        int colL = t & 127, seg = t >> 7;  // 8 segs x 128 cols
        int col = blockIdx.x * 128 + colL;
        float s = 0.0f;
#pragma unroll
        for (int j = 0; j < 32; ++j)
            s += P[(size_t)(seg * 32 + j) * D + col];
        red[seg][colL] = s;
        __syncthreads();
        if (t < 128) {
            float v = 0.0f;
#pragma unroll
            for (int k = 0; k < 8; ++k) v += red[k][t];
            colsum[blockIdx.x * 128 + t] = v;
        }
    } else {
        __shared__ float dec[NC];
        __shared__ float Pg[NG];
        if (t < NC)
            dec[t] = (t + 1 < NC) ? __expf(t_ev[t * C] - t_ev[(t + 1) * C]) : 1.0f;
        __syncthreads();
        if (t < NC) {
            int g = t >> 5, r = t & 31;
            float p = 1.0f;
            for (int j = 0; j < r; ++j) p *= dec[g * GC + j];
            cumdec[t] = p;
            if (r == GC - 1) Pg[g] = p * dec[t];
        }
        __syncthreads();
        float a[NG];
#pragma unroll
        for (int g2 = 0; g2 < NG; ++g2) a[g2] = A[(size_t)g2 * D + t];
        float S = 0.0f;
#pragma unroll
        for (int g2 = 0; g2 < NG; ++g2) {
            Sg[(size_t)g2 * D + t] = S;
            S = S * Pg[g2] + a[g2];
        }
    }
}

// main: 8 blocks per chunk (8 events each, 2 per wave — short latency chain),
// fused scan fixup + compensator. alpha read as bf16. No global atomics.
__launch_bounds__(256)
__global__ void k_main(const float* __restrict__ t_ev, const int* __restrict__ marks,
                       const unsigned short* __restrict__ ab, const float* __restrict__ mu,
                       const float* __restrict__ colsum, const float* __restrict__ Sl,
                       const float* __restrict__ Sg, const float* __restrict__ cumdec,
                       float* __restrict__ llp, float* __restrict__ compp) {
    __shared__ float S_lds[D];
    __shared__ float t_lds[C];
    __shared__ int d_lds[C];
    __shared__ float red[8];
    int t = threadIdx.x;
    int c = blockIdx.x >> 3, sub = blockIdx.x & 7;
    int g = c >> 5;
    float cd = cumdec[c];
#pragma unroll
    for (int q = 0; q < 4; ++q) {
        int k = t + 256 * q;
        S_lds[k] = Sl[(size_t)c * D + k] + Sg[(size_t)g * D + k] * cd;
    }
    if (t < C) {
        t_lds[t] = t_ev[c * C + t];
        d_lds[t] = marks[c * C + t];
    }
    __syncthreads();
    int wave = t >> 6, lane = t & 63;
    float t0 = t_lds[0];
    float ll_acc = 0.0f, comp_acc = 0.0f;
#pragma unroll
    for (int i = sub * 8 + wave; i < sub * 8 + 8; i += 4) {
        int row = d_lds[i];
        float ti = t_lds[i];
        float mu_r = mu[row];
        float cs_r = colsum[row];
        const uint4* arow = (const uint4*)(ab + (size_t)row * D);
        float acc_dot = 0.0f;
#pragma unroll
        for (int u = 0; u < 2; ++u) {
            uint4 pk = arow[2 * lane + u];  // 8 bf16: cols 16*lane+8u .. +7
            const float4* sp = (const float4*)(S_lds + 16 * lane + 8 * u);
            float4 s0 = sp[0], s1 = sp[1];
            acc_dot += __uint_as_float(pk.x << 16) * s0.x
                     + __uint_as_float(pk.x & 0xFFFF0000u) * s0.y
                     + __uint_as_float(pk.y << 16) * s0.z
                     + __uint_as_float(pk.y & 0xFFFF0000u) * s0.w
                     + __uint_as_float(pk.z << 16) * s1.x
                     + __uint_as_float(pk.z & 0xFFFF0000u) * s1.y
                     + __uint_as_float(pk.w << 16) * s1.z
                     + __uint_as_float(pk.w & 0xFFFF0000u) * s1.w;
        }
        float part = acc_dot * __expf(t0 - ti);
        if (lane < i) {
            part += bf2f(ab[(size_t)row * D + d_lds[lane]]) * __expf(t_lds[lane] - ti);
        }
#pragma unroll
        for (int off = 32; off > 0; off >>= 1) part += __shfl_xor(part, off);
        if (lane == 0) {
            ll_acc += __logf(mu_r + part + EPSLOG);
            comp_acc += cs_r * (1.0f - __expf(ti - TMAXV));
        }
    }
    if (lane == 0) {
        red[wave] = ll_acc;
        red[4 + wave] = comp_acc;
    }
    __syncthreads();
    if (t == 0) {
        llp[blockIdx.x] = red[0] + red[1] + red[2] + red[3];
        compp[blockIdx.x] = red[4] + red[5] + red[6] + red[7];
    }
}

// final: out = sum(llp) - (T*sum(mu) + sum(compp)). 1 block, 1024 threads.
__global__ void k_final(const float* __restrict__ llp, const float* __restrict__ compp,
                        const float* __restrict__ mu, float* __restrict__ out) {
    __shared__ float r_ll[1024], r_cm[1024], r_mu[1024];
    int t = threadIdx.x;
    float sll = 0.0f, scm = 0.0f;
#pragma unroll
    for (int j = 0; j < 4; ++j) {
        sll += llp[t + 1024 * j];
        scm += compp[t + 1024 * j];
    }
    r_ll[t] = sll;
    r_cm[t] = scm;
    r_mu[t] = mu[t];
    __syncthreads();
    for (int off = 512; off > 0; off >>= 1) {
        if (t < off) {
            r_ll[t] += r_ll[t + off];
            r_cm[t] += r_cm[t + off];
            r_mu[t] += r_mu[t + off];
        }
        __syncthreads();
    }
    if (t == 0) out[0] = r_ll[0] - (TMAXV * r_mu[0] + r_cm[0]);
}

extern "C" void kernel_launch(void* const* d_in, const int* in_sizes, int n_in,
                              void* d_out, int out_size, void* d_ws, size_t ws_size,
                              hipStream_t stream) {
    const float* t_ev = (const float*)d_in[0];
    const int* marks = (const int*)d_in[1];
    const float* log_mu = (const float*)d_in[2];
    const float* log_alpha = (const float*)d_in[3];
    float* out = (float*)d_out;

    float* w = (float*)d_ws;
    unsigned short* ab = (unsigned short*)w;        // D*D bf16 = D*D/2 floats
    float* Sl = w + (size_t)D * D / 2;              // NC*D
    float* mu = Sl + (size_t)NC * D;                // D
    float* colsum = mu + D;                         // D
    float* P = colsum + D;                          // 256*D (own buffer now)
    float* llp = P + (size_t)256 * D;               // NB
    float* compp = llp + NB;                        // NB
    float* A = compp + NB;                          // NG*D
    float* Sg = A + (size_t)NG * D;                 // NG*D
    float* cumdec = Sg + (size_t)NG * D;            // NC

    k_prep<<<257, 256, 0, stream>>>(log_alpha, log_mu, ab, mu, P);
    k_fused<<<64, 256, 0, stream>>>(t_ev, marks, Sl, A);
    k_mid<<<9, 1024, 0, stream>>>(P, colsum, t_ev, A, Sg, cumdec);
    k_main<<<NB, 256, 0, stream>>>(t_ev, marks, ab, mu, colsum, Sl, Sg, cumdec, llp, compp);
    k_final<<<1, 1024, 0, stream>>>(llp, compp, mu, out);
}

// Round 12
// 90.110 us; speedup vs baseline: 2.4028x; 1.0435x over previous
//
#include <hip/hip_runtime.h>

// Hawkes log-likelihood, D=1024 dims, M=32768 events, BETA=1.
//
// lam_i = mu[d_i] + sum_{j<i} alpha[d_i,d_j] * exp(t_j - t_i).
// Chunk events into NC=512 chunks of C=64:
//   cross-chunk: exp(t_c0 - t_i) * dot(alpha[d_i,:], S_c)
//   in-chunk:    one lane-parallel predicated gather step (C == wave size)
// S_c via TWO-LEVEL dimension-parallel scan; level-1 histogram+scan fused in
// LDS; level-2 fixup S = Sl + Sg*cumdec fused into k_main's S load.
// Compensator: sum_i colsum[d_i] * (1 - exp(t_i - T)) fused into k_main.
//
// Lessons: R2 — same-cacheline global atomics serialize (~15ns) -> zero
// global atomics; grid-wide completion counters rejected for the same
// reason. R5 — single-block LDS-atomic histogram = 43us on one CU. R6 —
// DEEP dependent-chain roles must not be merged (regalloc pessimization);
// SHALLOW roles are safe (R11's k_mid verified). R9 — wide colred. R10 —
// bf16 alpha. R11 — 8 blocks/chunk k_main + k_mid merge. R12 — k_prep and
// k_fused merged into k1 (both read only raw inputs; 4 dispatches total).
//
// ws floats: ab(bf16)[D*D] | Sl[NC*D] | mu[D] | colsum[D] | P[256*D] |
//            llp[NB] | compp[NB] | A[NG*D] | Sg[NG*D] | cumdec[NC]  (~5.5MB)

#define D 1024
#define M 32768
#define C 64
#define NC (M / C)   /* 512 */
#define NB (NC * 8)  /* k_main blocks: 4096 */
#define NG 16        /* scan groups */
#define GC (NC / NG) /* 32 chunks per group */
#define TMAXV 1000.0f
#define EPSMU 1e-6f
#define EPSLOG 1e-8f

__device__ __forceinline__ float softplus(float x) {
    return (x > 0.0f) ? (x + log1pf(__expf(-x))) : log1pf(__expf(x));
}

// round-to-nearest-even fp32 -> bf16 (inputs are positive finite)
__device__ __forceinline__ unsigned short f2bf(float x) {
    unsigned u = __float_as_uint(x);
    return (unsigned short)((u + 0x7FFFu + ((u >> 16) & 1u)) >> 16);
}
__device__ __forceinline__ float bf2f(unsigned short h) {
    return __uint_as_float(((unsigned)h) << 16);
}

// Stage 1, one kernel, disjoint block roles; ALL roles read only raw inputs:
//   b in [0,256):   softplus(alpha) 4-row tile -> bf16 ab + fp32 colsum partial P
//   b == 256:       mu = softplus(log_mu) + eps
//   b in [257,321): fused level-1: per-chunk LDS histogram + LDS scan
//                   (16 groups x 4 dim-slices; writes Sl prefix + aggregate A)
// Both roles are SHALLOW chains (R6 lesson respected).
__global__ void k1(const float* __restrict__ t_ev, const int* __restrict__ marks,
                   const float* __restrict__ log_alpha, const float* __restrict__ log_mu,
                   unsigned short* __restrict__ ab, float* __restrict__ mu,
                   float* __restrict__ P, float* __restrict__ Sl, float* __restrict__ A) {
    __shared__ float Lh[GC * 256];  // 32 KB (fused role only)
    __shared__ float dec[GC];
    __shared__ float tns[GC];
    int t = threadIdx.x;
    int b = blockIdx.x;

    if (b < 256) {
        int r0 = b * 4;
        float4 cs = {0.f, 0.f, 0.f, 0.f};
        for (int r = 0; r < 4; ++r) {
            const float4* src = (const float4*)(log_alpha + (size_t)(r0 + r) * D);
            float4 v = src[t];
            float4 a;
            a.x = softplus(v.x);
            a.y = softplus(v.y);
            a.z = softplus(v.z);
            a.w = softplus(v.w);
            cs.x += a.x; cs.y += a.y; cs.z += a.z; cs.w += a.w;
            ushort4 h;
            h.x = f2bf(a.x); h.y = f2bf(a.y); h.z = f2bf(a.z); h.w = f2bf(a.w);
            ((ushort4*)(ab + (size_t)(r0 + r) * D))[t] = h;
        }
        ((float4*)(P + (size_t)b * D))[t] = cs;  // P[b][col], col = 4t+j
    } else if (b == 256) {
#pragma unroll
        for (int q = 0; q < 4; ++q) {
            int k = t + 256 * q;
            mu[k] = softplus(log_mu[k]) + EPSMU;
        }
    } else {
        int fb = b - 257;            // 0..63
        int g = fb >> 2, db = fb & 3;
#pragma unroll
        for (int q = 0; q < GC; ++q) Lh[q * 256 + t] = 0.0f;
        if (t < GC) {
            int gc = g * GC + t;
            float tn = (gc + 1 < NC) ? t_ev[(gc + 1) * C] : t_ev[M - 1];
            tns[t] = tn;
            dec[t] = (gc + 1 < NC) ? __expf(t_ev[gc * C] - tn) : 1.0f;
        }
        __syncthreads();
        int base = g * (GC * C);  // 2048 events per group
#pragma unroll
        for (int it = 0; it < 8; ++it) {
            int e = it * 256 + t;
            float te = t_ev[base + e];
            int m = marks[base + e];
            int lc = e >> 6;
            int ml = m - db * 256;
            if ((unsigned)ml < 256u) atomicAdd(&Lh[lc * 256 + ml], __expf(te - tns[lc]));
        }
        __syncthreads();
        int k = db * 256 + t;
        float S = 0.0f;
        for (int lc = 0; lc < GC; ++lc) {
            Sl[(size_t)(g * GC + lc) * D + k] = S;
            S = S * dec[lc] + Lh[lc * 256 + t];
        }
        A[(size_t)g * D + k] = S;
    }
}

// Merged mid-stage, 9 blocks x 1024 threads (both roles SHALLOW):
//   blocks 0..7: reduce P[256][D] -> colsum (128 cols/block, 8 segs x 32 rows)
//   block 8:     level-2 scan over 16 group aggregates + per-chunk cumdec
__global__ void k_mid(const float* __restrict__ P, float* __restrict__ colsum,
                      const float* __restrict__ t_ev, const float* __restrict__ A,
                      float* __restrict__ Sg, float* __restrict__ cumdec) {
    int t = threadIdx.x;
    if (blockIdx.x < 8) {
        __shared__ float red[8][128];
        int colL = t & 127, seg = t >> 7;  // 8 segs x 128 cols
        int col = blockIdx.x * 128 + colL;
        float s = 0.0f;
#pragma unroll
        for (int j = 0; j < 32; ++j)
            s += P[(size_t)(seg * 32 + j) * D + col];
        red[seg][colL] = s;
        __syncthreads();
        if (t < 128) {
            float v = 0.0f;
#pragma unroll
            for (int k = 0; k < 8; ++k) v += red[k][t];
            colsum[blockIdx.x * 128 + t] = v;
        }
    } else {
        __shared__ float dec[NC];
        __shared__ float Pg[NG];
        if (t < NC)
            dec[t] = (t + 1 < NC) ? __expf(t_ev[t * C] - t_ev[(t + 1) * C]) : 1.0f;
        __syncthreads();
        if (t < NC) {
            int g = t >> 5, r = t & 31;
            float p = 1.0f;
            for (int j = 0; j < r; ++j) p *= dec[g * GC + j];
            cumdec[t] = p;
            if (r == GC - 1) Pg[g] = p * dec[t];
        }
        __syncthreads();
        float a[NG];
#pragma unroll
        for (int g2 = 0; g2 < NG; ++g2) a[g2] = A[(size_t)g2 * D + t];
        float S = 0.0f;
#pragma unroll
        for (int g2 = 0; g2 < NG; ++g2) {
            Sg[(size_t)g2 * D + t] = S;
            S = S * Pg[g2] + a[g2];
        }
    }
}

// main: 8 blocks per chunk (8 events each, 2 per wave), fused scan fixup +
// compensator. alpha read as bf16. Per-block partials, no global atomics.
__launch_bounds__(256)
__global__ void k_main(const float* __restrict__ t_ev, const int* __restrict__ marks,
                       const unsigned short* __restrict__ ab, const float* __restrict__ mu,
                       const float* __restrict__ colsum, const float* __restrict__ Sl,
                       const float* __restrict__ Sg, const float* __restrict__ cumdec,
                       float* __restrict__ llp, float* __restrict__ compp) {
    __shared__ float S_lds[D];
    __shared__ float t_lds[C];
    __shared__ int d_lds[C];
    __shared__ float red[8];
    int t = threadIdx.x;
    int c = blockIdx.x >> 3, sub = blockIdx.x & 7;
    int g = c >> 5;
    float cd = cumdec[c];
#pragma unroll
    for (int q = 0; q < 4; ++q) {
        int k = t + 256 * q;
        S_lds[k] = Sl[(size_t)c * D + k] + Sg[(size_t)g * D + k] * cd;
    }
    if (t < C) {
        t_lds[t] = t_ev[c * C + t];
        d_lds[t] = marks[c * C + t];
    }
    __syncthreads();
    int wave = t >> 6, lane = t & 63;
    float t0 = t_lds[0];
    float ll_acc = 0.0f, comp_acc = 0.0f;
#pragma unroll
    for (int i = sub * 8 + wave; i < sub * 8 + 8; i += 4) {
        int row = d_lds[i];
        float ti = t_lds[i];
        float mu_r = mu[row];
        float cs_r = colsum[row];
        const uint4* arow = (const uint4*)(ab + (size_t)row * D);
        float acc_dot = 0.0f;
#pragma unroll
        for (int u = 0; u < 2; ++u) {
            uint4 pk = arow[2 * lane + u];  // 8 bf16: cols 16*lane+8u .. +7
            const float4* sp = (const float4*)(S_lds + 16 * lane + 8 * u);
            float4 s0 = sp[0], s1 = sp[1];
            acc_dot += __uint_as_float(pk.x << 16) * s0.x
                     + __uint_as_float(pk.x & 0xFFFF0000u) * s0.y
                     + __uint_as_float(pk.y << 16) * s0.z
                     + __uint_as_float(pk.y & 0xFFFF0000u) * s0.w
                     + __uint_as_float(pk.z << 16) * s1.x
                     + __uint_as_float(pk.z & 0xFFFF0000u) * s1.y
                     + __uint_as_float(pk.w << 16) * s1.z
                     + __uint_as_float(pk.w & 0xFFFF0000u) * s1.w;
        }
        float part = acc_dot * __expf(t0 - ti);
        if (lane < i) {
            part += bf2f(ab[(size_t)row * D + d_lds[lane]]) * __expf(t_lds[lane] - ti);
        }
#pragma unroll
        for (int off = 32; off > 0; off >>= 1) part += __shfl_xor(part, off);
        if (lane == 0) {
            ll_acc += __logf(mu_r + part + EPSLOG);
            comp_acc += cs_r * (1.0f - __expf(ti - TMAXV));
        }
    }
    if (lane == 0) {
        red[wave] = ll_acc;
        red[4 + wave] = comp_acc;
    }
    __syncthreads();
    if (t == 0) {
        llp[blockIdx.x] = red[0] + red[1] + red[2] + red[3];
        compp[blockIdx.x] = red[4] + red[5] + red[6] + red[7];
    }
}

// final: out = sum(llp) - (T*sum(mu) + sum(compp)). 1 block, 1024 threads.
__global__ void k_final(const float* __restrict__ llp, const float* __restrict__ compp,
                        const float* __restrict__ mu, float* __restrict__ out) {
    __shared__ float r_ll[1024], r_cm[1024], r_mu[1024];
    int t = threadIdx.x;
    float sll = 0.0f, scm = 0.0f;
#pragma unroll
    for (int j = 0; j < 4; ++j) {
        sll += llp[t + 1024 * j];
        scm += compp[t + 1024 * j];
    }
    r_ll[t] = sll;
    r_cm[t] = scm;
    r_mu[t] = mu[t];
    __syncthreads();
    for (int off = 512; off > 0; off >>= 1) {
        if (t < off) {
            r_ll[t] += r_ll[t + off];
            r_cm[t] += r_cm[t + off];
            r_mu[t] += r_mu[t + off];
        }
        __syncthreads();
    }
    if (t == 0) out[0] = r_ll[0] - (TMAXV * r_mu[0] + r_cm[0]);
}

extern "C" void kernel_launch(void* const* d_in, const int* in_sizes, int n_in,
                              void* d_out, int out_size, void* d_ws, size_t ws_size,
                              hipStream_t stream) {
    const float* t_ev = (const float*)d_in[0];
    const int* marks = (const int*)d_in[1];
    const float* log_mu = (const float*)d_in[2];
    const float* log_alpha = (const float*)d_in[3];
    float* out = (float*)d_out;

    float* w = (float*)d_ws;
    unsigned short* ab = (unsigned short*)w;        // D*D bf16 = D*D/2 floats
    float* Sl = w + (size_t)D * D / 2;              // NC*D
    float* mu = Sl + (size_t)NC * D;                // D
    float* colsum = mu + D;                         // D
    float* P = colsum + D;                          // 256*D
    float* llp = P + (size_t)256 * D;               // NB
    float* compp = llp + NB;                        // NB
    float* A = compp + NB;                          // NG*D
    float* Sg = A + (size_t)NG * D;                 // NG*D
    float* cumdec = Sg + (size_t)NG * D;            // NC

    k1<<<321, 256, 0, stream>>>(t_ev, marks, log_alpha, log_mu, ab, mu, P, Sl, A);
    k_mid<<<9, 1024, 0, stream>>>(P, colsum, t_ev, A, Sg, cumdec);
    k_main<<<NB, 256, 0, stream>>>(t_ev, marks, ab, mu, colsum, Sl, Sg, cumdec, llp, compp);
    k_final<<<1, 1024, 0, stream>>>(llp, compp, mu, out);
}